// Round 1
// baseline (2807.583 us; speedup 1.0000x reference)
//
#include <hip/hip_runtime.h>
#include <hip/hip_bf16.h>
#include <math.h>

// Problem constants
#define BB 8
#define LLEN 1024
#define DDIM 512
#define HH 8
#define DK 64
#define DLAT 512
#define NROW (BB * LLEN)        // 8192
#define ROWELEM 4194304         // 8192*512

// ---------------------------------------------------------------------------
// Generic fp32 GEMM: C[M,N] = A[M,K] @ W[K,N] + bias[N]
// 64x64 block tile, BK=16, 256 threads, 4x4 per thread.
// ---------------------------------------------------------------------------
__global__ __launch_bounds__(256) void gemm_bias_kernel(
    const float* __restrict__ A, const float* __restrict__ W,
    const float* __restrict__ bias, float* __restrict__ C,
    int M, int N, int K)
{
    const int tid = threadIdx.x;
    const int tx = tid & 15, ty = tid >> 4;
    const int col0 = blockIdx.x * 64, row0 = blockIdx.y * 64;

    __shared__ float As[16][65];   // [k][m]
    __shared__ float Bs[16][65];   // [k][n]

    float acc[4][4] = {};

    for (int k0 = 0; k0 < K; k0 += 16) {
        #pragma unroll
        for (int l = 0; l < 4; ++l) {
            int idx = tid + l * 256;          // 0..1023
            int r = idx >> 4, c = idx & 15;
            As[c][r] = A[(size_t)(row0 + r) * K + k0 + c];
        }
        #pragma unroll
        for (int l = 0; l < 4; ++l) {
            int idx = tid + l * 256;
            int r = idx >> 6, c = idx & 63;
            Bs[r][c] = W[(size_t)(k0 + r) * N + col0 + c];
        }
        __syncthreads();
        #pragma unroll
        for (int kk = 0; kk < 16; ++kk) {
            float a[4], b[4];
            #pragma unroll
            for (int i = 0; i < 4; ++i) a[i] = As[kk][ty * 4 + i];
            #pragma unroll
            for (int j = 0; j < 4; ++j) b[j] = Bs[kk][tx * 4 + j];
            #pragma unroll
            for (int i = 0; i < 4; ++i)
                #pragma unroll
                for (int j = 0; j < 4; ++j) acc[i][j] += a[i] * b[j];
        }
        __syncthreads();
    }

    #pragma unroll
    for (int i = 0; i < 4; ++i) {
        int r = row0 + ty * 4 + i;
        #pragma unroll
        for (int j = 0; j < 4; ++j) {
            int c = col0 + tx * 4 + j;
            C[(size_t)r * N + c] = acc[i][j] + bias[c];
        }
    }
}

// ---------------------------------------------------------------------------
// FiLM latent: film[b, 0:1024] = silu(latent[b,:]) @ Ws1 + bs1
// grid (B, 4), block 256 -> each thread one output column
// ---------------------------------------------------------------------------
__global__ __launch_bounds__(256) void film_latent_kernel(
    const float* __restrict__ latent, const float* __restrict__ Ws1,
    const float* __restrict__ bs1, float* __restrict__ film)
{
    __shared__ float sl[DLAT];
    const int b = blockIdx.x;
    const int tid = threadIdx.x;
    #pragma unroll
    for (int l = 0; l < 2; ++l) {
        int k = tid + l * 256;
        float x = latent[b * DLAT + k];
        sl[k] = x / (1.f + __expf(-x));
    }
    __syncthreads();
    int n = blockIdx.y * 256 + tid;
    float acc = bs1[n];
    for (int k = 0; k < DLAT; ++k)
        acc += sl[k] * Ws1[(size_t)k * 1024 + n];
    film[b * 1024 + n] = acc;
}

// ---------------------------------------------------------------------------
// Attention: one block handles (b, h, 16-query tile). Keeps the full score
// row S[16][1024] in LDS; computes softmax there; writes normalized attn
// once (coalesced); then P@V accumulated in registers.
// ---------------------------------------------------------------------------
__global__ __launch_bounds__(256) void attn_kernel(
    const float* __restrict__ Qp, const float* __restrict__ Kp,
    const float* __restrict__ Vp, float* __restrict__ attn_out,
    float* __restrict__ o_out)
{
    const int blk = blockIdx.x;           // 0..4095
    const int qt = blk & 63;
    const int h  = (blk >> 6) & 7;
    const int b  = blk >> 9;
    const int q0 = qt * 16;
    const int tid = threadIdx.x;

    __shared__ float S[16][1025];
    __shared__ float Qs[16][65];
    __shared__ float Ks[64][65];
    __shared__ float red[16][17];
    __shared__ float rowm[16], rowinv[16];

    // load Q tile
    #pragma unroll
    for (int l = 0; l < 4; ++l) {
        int idx = tid + l * 256;
        int i = idx >> 6, d = idx & 63;
        Qs[i][d] = Qp[((size_t)(b * LLEN + q0 + i)) * DDIM + h * 64 + d];
    }

    const int j  = tid & 63;   // key col within tile / output dim
    const int ib = tid >> 6;   // 0..3

    // ---- scores ----
    for (int kt = 0; kt < 16; ++kt) {
        __syncthreads();
        #pragma unroll
        for (int l = 0; l < 16; ++l) {
            int idx = tid + l * 256;
            int r = idx >> 6, d = idx & 63;
            Ks[r][d] = Kp[((size_t)(b * LLEN + kt * 64 + r)) * DDIM + h * 64 + d];
        }
        __syncthreads();
        #pragma unroll
        for (int l = 0; l < 4; ++l) {
            int i = ib + l * 4;
            float acc = 0.f;
            #pragma unroll 8
            for (int d = 0; d < 64; ++d) acc += Qs[i][d] * Ks[j][d];
            S[i][kt * 64 + j] = acc * 0.125f;
        }
    }
    __syncthreads();

    // ---- softmax (16 threads per row) ----
    {
        const int i = tid >> 4;
        const int c = tid & 15;
        float m = -1e30f;
        for (int s = c; s < 1024; s += 16) m = fmaxf(m, S[i][s]);
        red[i][c] = m;
        __syncthreads();
        if (c == 0) {
            float mm = red[i][0];
            for (int t = 1; t < 16; ++t) mm = fmaxf(mm, red[i][t]);
            rowm[i] = mm;
        }
        __syncthreads();
        float mm = rowm[i];
        float sum = 0.f;
        for (int s = c; s < 1024; s += 16) {
            float e = __expf(S[i][s] - mm);
            S[i][s] = e;
            sum += e;
        }
        red[i][c] = sum;
        __syncthreads();
        if (c == 0) {
            float ss = 0.f;
            for (int t = 0; t < 16; ++t) ss += red[i][t];
            rowinv[i] = 1.f / ss;
        }
        __syncthreads();
    }

    // ---- normalize + write attn (coalesced) ----
    {
        const size_t abase = ((size_t)(b * HH + h) * LLEN + q0) * LLEN;
        #pragma unroll 4
        for (int l = 0; l < 64; ++l) {
            int idx = tid + l * 256;
            int ii = idx >> 10, k = idx & 1023;
            float p = S[ii][k] * rowinv[ii];
            S[ii][k] = p;
            attn_out[abase + (size_t)ii * LLEN + k] = p;
        }
    }
    __syncthreads();

    // ---- o = P @ V ----
    float acco[4] = {0.f, 0.f, 0.f, 0.f};
    for (int kt = 0; kt < 16; ++kt) {
        __syncthreads();
        #pragma unroll
        for (int l = 0; l < 16; ++l) {
            int idx = tid + l * 256;
            int r = idx >> 6, d = idx & 63;
            Ks[r][d] = Vp[((size_t)(b * LLEN + kt * 64 + r)) * DDIM + h * 64 + d];
        }
        __syncthreads();
        #pragma unroll
        for (int l = 0; l < 4; ++l) {
            int ii = ib + l * 4;
            #pragma unroll 8
            for (int r = 0; r < 64; ++r)
                acco[l] += S[ii][kt * 64 + r] * Ks[r][j];
        }
    }
    #pragma unroll
    for (int l = 0; l < 4; ++l) {
        int ii = ib + l * 4;
        o_out[((size_t)(b * LLEN + q0 + ii)) * DDIM + h * 64 + j] = acco[l];
    }
}

// ---------------------------------------------------------------------------
// block-wide 2-value sum reduction (256 threads)
// ---------------------------------------------------------------------------
__device__ inline void block_reduce2(float& a, float& b) {
    #pragma unroll
    for (int off = 32; off > 0; off >>= 1) {
        a += __shfl_down(a, off, 64);
        b += __shfl_down(b, off, 64);
    }
    __shared__ float wa[4], wb[4];
    int lane = threadIdx.x & 63, w = threadIdx.x >> 6;
    if (lane == 0) { wa[w] = a; wb[w] = b; }
    __syncthreads();
    if (threadIdx.x == 0) {
        wa[0] = wa[0] + wa[1] + wa[2] + wa[3];
        wb[0] = wb[0] + wb[1] + wb[2] + wb[3];
    }
    __syncthreads();
    a = wa[0];
    b = wb[0];
}

// ---------------------------------------------------------------------------
// FiLM apply: h = LN(X, en_g, en_b, 1e-5) * (1+scale) + shift; HS = silu(h)
// one block per row (512 cols, 2 per thread)
// ---------------------------------------------------------------------------
__global__ __launch_bounds__(256) void film_ln_kernel(
    const float* __restrict__ X, const float* __restrict__ en_g,
    const float* __restrict__ en_b, const float* __restrict__ film,
    float* __restrict__ HS)
{
    const int row = blockIdx.x;
    const int b = row >> 10;
    const int tid = threadIdx.x;
    const size_t base = (size_t)row * DDIM;

    float x0 = X[base + tid];
    float x1 = X[base + 256 + tid];
    float s = x0 + x1;
    float s2 = x0 * x0 + x1 * x1;
    block_reduce2(s, s2);
    float mean = s * (1.f / 512.f);
    float var = s2 * (1.f / 512.f) - mean * mean;
    float inv = rsqrtf(var + 1e-5f);

    #pragma unroll
    for (int l = 0; l < 2; ++l) {
        int d = tid + l * 256;
        float x = (l == 0) ? x0 : x1;
        float nh = (x - mean) * inv * en_g[d] + en_b[d];
        float sc = film[b * 1024 + d];
        float sh = film[b * 1024 + 512 + d];
        float hv = nh * (1.f + sc) + sh;
        HS[base + d] = hv / (1.f + __expf(-hv));
    }
}

// ---------------------------------------------------------------------------
// Final: out = LN(H2 + resid, ln_g, ln_b, 1e-6)
// ---------------------------------------------------------------------------
__global__ __launch_bounds__(256) void final_ln_kernel(
    const float* __restrict__ H2, const float* __restrict__ resid,
    const float* __restrict__ g, const float* __restrict__ bta,
    float* __restrict__ out)
{
    const int row = blockIdx.x;
    const int tid = threadIdx.x;
    const size_t base = (size_t)row * DDIM;

    float x0 = H2[base + tid] + resid[base + tid];
    float x1 = H2[base + 256 + tid] + resid[base + 256 + tid];
    float s = x0 + x1;
    float s2 = x0 * x0 + x1 * x1;
    block_reduce2(s, s2);
    float mean = s * (1.f / 512.f);
    float var = s2 * (1.f / 512.f) - mean * mean;
    float inv = rsqrtf(var + 1e-6f);

    #pragma unroll
    for (int l = 0; l < 2; ++l) {
        int d = tid + l * 256;
        float x = (l == 0) ? x0 : x1;
        out[base + d] = (x - mean) * inv * g[d] + bta[d];
    }
}

// ---------------------------------------------------------------------------
extern "C" void kernel_launch(void* const* d_in, const int* in_sizes, int n_in,
                              void* d_out, int out_size, void* d_ws, size_t ws_size,
                              hipStream_t stream)
{
    const float* q      = (const float*)d_in[0];
    const float* k      = (const float*)d_in[1];
    const float* v      = (const float*)d_in[2];
    const float* latent = (const float*)d_in[3];
    const float* Wq  = (const float*)d_in[4];
    const float* bq  = (const float*)d_in[5];
    const float* Wk  = (const float*)d_in[6];
    const float* bk  = (const float*)d_in[7];
    const float* Wv  = (const float*)d_in[8];
    const float* bv  = (const float*)d_in[9];
    const float* Wfc = (const float*)d_in[10];
    const float* bfc = (const float*)d_in[11];
    const float* Ws1 = (const float*)d_in[12];
    const float* bs1 = (const float*)d_in[13];
    const float* Ws2 = (const float*)d_in[14];
    const float* bs2 = (const float*)d_in[15];
    const float* en_g = (const float*)d_in[16];
    const float* en_b = (const float*)d_in[17];
    const float* ln_g = (const float*)d_in[18];
    const float* ln_b = (const float*)d_in[19];

    float* out  = (float*)d_out;            // [8192, 512]
    float* attn = out + ROWELEM;            // [8, 8, 1024, 1024]

    float* ws = (float*)d_ws;
    float* Qp   = ws;                       // 4194304 floats
    float* Kp   = Qp + ROWELEM;
    float* Vp   = Kp + ROWELEM;
    float* Ob   = Vp + ROWELEM;
    float* film = Ob + ROWELEM;             // 8192 floats
    // reuse after attention: fc_out = Qp, HS = Kp, H2 = Vp

    dim3 ggrid(8, 128);

    gemm_bias_kernel<<<ggrid, 256, 0, stream>>>(q, Wq, bq, Qp, NROW, 512, 512);
    gemm_bias_kernel<<<ggrid, 256, 0, stream>>>(k, Wk, bk, Kp, NROW, 512, 512);
    gemm_bias_kernel<<<ggrid, 256, 0, stream>>>(v, Wv, bv, Vp, NROW, 512, 512);

    film_latent_kernel<<<dim3(BB, 4), 256, 0, stream>>>(latent, Ws1, bs1, film);

    attn_kernel<<<4096, 256, 0, stream>>>(Qp, Kp, Vp, attn, Ob);

    gemm_bias_kernel<<<ggrid, 256, 0, stream>>>(Ob, Wfc, bfc, Qp, NROW, 512, 512);

    film_ln_kernel<<<NROW, 256, 0, stream>>>(Qp, en_g, en_b, film, Kp);

    gemm_bias_kernel<<<ggrid, 256, 0, stream>>>(Kp, Ws2, bs2, Vp, NROW, 512, 512);

    final_ln_kernel<<<NROW, 256, 0, stream>>>(Vp, q, ln_g, ln_b, out);
}

// Round 2
// 901.815 us; speedup vs baseline: 3.1133x; 3.1133x over previous
//
#include <hip/hip_runtime.h>
#include <hip/hip_bf16.h>
#include <math.h>

// Problem constants
#define BB 8
#define LLEN 1024
#define DDIM 512
#define HH 8
#define DLAT 512
#define NROW (BB * LLEN)        // 8192
#define ROWELEM 4194304         // 8192*512

typedef __bf16 bf16x8 __attribute__((ext_vector_type(8)));
typedef __bf16 bf16x4 __attribute__((ext_vector_type(4)));
typedef float  f32x4  __attribute__((ext_vector_type(4)));

__device__ inline __bf16 f2bf(float f) {
    union { float f; unsigned u; } a; a.f = f;
    unsigned r = (a.u + 0x7fffu + ((a.u >> 16) & 1u)) >> 16;
    union { unsigned short s; __bf16 b; } o; o.s = (unsigned short)r;
    return o.b;
}

// ---------------------------------------------------------------------------
// fp32 GEMM: C[M,N] = A[M,K] @ W[K,N] + bias[N]   (fp32 out)
// ---------------------------------------------------------------------------
__global__ __launch_bounds__(256) void gemm_bias_kernel(
    const float* __restrict__ A, const float* __restrict__ W,
    const float* __restrict__ bias, float* __restrict__ C,
    int M, int N, int K)
{
    const int tid = threadIdx.x;
    const int tx = tid & 15, ty = tid >> 4;
    const int col0 = blockIdx.x * 64, row0 = blockIdx.y * 64;

    __shared__ float As[16][65];
    __shared__ float Bs[16][65];

    float acc[4][4] = {};

    for (int k0 = 0; k0 < K; k0 += 16) {
        #pragma unroll
        for (int l = 0; l < 4; ++l) {
            int idx = tid + l * 256;
            int r = idx >> 4, c = idx & 15;
            As[c][r] = A[(size_t)(row0 + r) * K + k0 + c];
        }
        #pragma unroll
        for (int l = 0; l < 4; ++l) {
            int idx = tid + l * 256;
            int r = idx >> 6, c = idx & 63;
            Bs[r][c] = W[(size_t)(k0 + r) * N + col0 + c];
        }
        __syncthreads();
        #pragma unroll
        for (int kk = 0; kk < 16; ++kk) {
            float a[4], b[4];
            #pragma unroll
            for (int i = 0; i < 4; ++i) a[i] = As[kk][ty * 4 + i];
            #pragma unroll
            for (int j = 0; j < 4; ++j) b[j] = Bs[kk][tx * 4 + j];
            #pragma unroll
            for (int i = 0; i < 4; ++i)
                #pragma unroll
                for (int j = 0; j < 4; ++j) acc[i][j] += a[i] * b[j];
        }
        __syncthreads();
    }

    #pragma unroll
    for (int i = 0; i < 4; ++i) {
        int r = row0 + ty * 4 + i;
        #pragma unroll
        for (int j = 0; j < 4; ++j) {
            int c = col0 + tx * 4 + j;
            C[(size_t)r * N + c] = acc[i][j] + bias[c];
        }
    }
}

// ---------------------------------------------------------------------------
// fp32 GEMM with bf16 output (packed 8B stores)
// ---------------------------------------------------------------------------
__global__ __launch_bounds__(256) void gemm_bias_bf16_kernel(
    const float* __restrict__ A, const float* __restrict__ W,
    const float* __restrict__ bias, __bf16* __restrict__ C,
    int M, int N, int K)
{
    const int tid = threadIdx.x;
    const int tx = tid & 15, ty = tid >> 4;
    const int col0 = blockIdx.x * 64, row0 = blockIdx.y * 64;

    __shared__ float As[16][65];
    __shared__ float Bs[16][65];

    float acc[4][4] = {};

    for (int k0 = 0; k0 < K; k0 += 16) {
        #pragma unroll
        for (int l = 0; l < 4; ++l) {
            int idx = tid + l * 256;
            int r = idx >> 4, c = idx & 15;
            As[c][r] = A[(size_t)(row0 + r) * K + k0 + c];
        }
        #pragma unroll
        for (int l = 0; l < 4; ++l) {
            int idx = tid + l * 256;
            int r = idx >> 6, c = idx & 63;
            Bs[r][c] = W[(size_t)(k0 + r) * N + col0 + c];
        }
        __syncthreads();
        #pragma unroll
        for (int kk = 0; kk < 16; ++kk) {
            float a[4], b[4];
            #pragma unroll
            for (int i = 0; i < 4; ++i) a[i] = As[kk][ty * 4 + i];
            #pragma unroll
            for (int j = 0; j < 4; ++j) b[j] = Bs[kk][tx * 4 + j];
            #pragma unroll
            for (int i = 0; i < 4; ++i)
                #pragma unroll
                for (int j = 0; j < 4; ++j) acc[i][j] += a[i] * b[j];
        }
        __syncthreads();
    }

    #pragma unroll
    for (int i = 0; i < 4; ++i) {
        int r = row0 + ty * 4 + i;
        bf16x4 pk;
        #pragma unroll
        for (int j = 0; j < 4; ++j) pk[j] = f2bf(acc[i][j] + bias[col0 + tx * 4 + j]);
        *(bf16x4*)(C + (size_t)r * N + col0 + tx * 4) = pk;
    }
}

// ---------------------------------------------------------------------------
// V transpose: Vb[b,l,h,d] bf16 -> VtG[b,h,d,l] bf16  (register transpose)
// ---------------------------------------------------------------------------
__global__ __launch_bounds__(256) void vtrans_kernel(
    const __bf16* __restrict__ Vb, __bf16* __restrict__ VtG)
{
    const int tid = threadIdx.x;
    const int lt = blockIdx.x & 15, h = (blockIdx.x >> 4) & 7, b = blockIdx.x >> 7;
    #pragma unroll
    for (int rep = 0; rep < 2; ++rep) {
        int s = tid + rep * 256;
        int r = s >> 3, c = s & 7;           // r: l within tile, c: d-chunk
        bf16x8 vld = *(const bf16x8*)(Vb + (size_t)(b * LLEN + lt * 64 + r) * DDIM + h * 64 + c * 8);
        #pragma unroll
        for (int j = 0; j < 8; ++j)
            VtG[((size_t)((b * 8 + h) * 64 + c * 8 + j)) * LLEN + lt * 64 + r] = vld[j];
    }
}

// ---------------------------------------------------------------------------
// FiLM latent
// ---------------------------------------------------------------------------
__global__ __launch_bounds__(256) void film_latent_kernel(
    const float* __restrict__ latent, const float* __restrict__ Ws1,
    const float* __restrict__ bs1, float* __restrict__ film)
{
    __shared__ float sl[DLAT];
    const int b = blockIdx.x;
    const int tid = threadIdx.x;
    #pragma unroll
    for (int l = 0; l < 2; ++l) {
        int k = tid + l * 256;
        float x = latent[b * DLAT + k];
        sl[k] = x / (1.f + __expf(-x));
    }
    __syncthreads();
    int n = blockIdx.y * 256 + tid;
    float acc = bs1[n];
    for (int k = 0; k < DLAT; ++k)
        acc += sl[k] * Ws1[(size_t)k * 1024 + n];
    film[b * 1024 + n] = acc;
}

// ---------------------------------------------------------------------------
// MFMA attention. Block = 4 waves = 64 queries of one (b,h). Each wave owns
// 16 queries (as the N dim of S^T = K Q^T). Two passes over K tiles:
//  pass1: row sums of exp(s/8); pass2: P write (dwordx4), P->LDS, PV MFMA.
// ---------------------------------------------------------------------------
__global__ __launch_bounds__(256) void attn_mfma_kernel(
    const __bf16* __restrict__ Qb, const __bf16* __restrict__ Kb,
    const __bf16* __restrict__ VtG, float* __restrict__ attn_out,
    float* __restrict__ o_out)
{
    const int bid = blockIdx.x;
    const int qt = bid & 15;
    const int h  = (bid >> 4) & 7;
    const int b  = bid >> 7;
    const int q0 = qt * 64;
    const int tid = threadIdx.x;
    const int w    = tid >> 6;
    const int lane = tid & 63;
    const int quad = lane >> 4;
    const int lid  = lane & 15;

    __shared__ __bf16 KtS[64][72];
    __shared__ __bf16 VtS[64][72];
    __shared__ __bf16 PtS[4][16][72];

    // Q fragments (B operand: B[k=d][n=q], lane holds n=lid, k=quad*8+j)
    const int myq = q0 + w * 16 + lid;
    const __bf16* qptr = Qb + (size_t)(b * LLEN + myq) * DDIM + h * 64 + quad * 8;
    const bf16x8 qf0 = *(const bf16x8*)(qptr);
    const bf16x8 qf1 = *(const bf16x8*)(qptr + 32);

    const size_t kbase = (size_t)(b * LLEN) * DDIM + h * 64;
    const size_t vbase = (size_t)((b * 8 + h) * 64) * LLEN;
    const f32x4 zero = {0.f, 0.f, 0.f, 0.f};
    const float C0 = 0.125f;

    // ---------------- pass 1: row sums ----------------
    float rsum = 0.f;
    for (int kt = 0; kt < 16; ++kt) {
        __syncthreads();
        #pragma unroll
        for (int rep = 0; rep < 2; ++rep) {
            int s = tid + rep * 256;
            int r = s >> 3, c = s & 7;
            *(bf16x8*)&KtS[r][c * 8] =
                *(const bf16x8*)(Kb + kbase + (size_t)(kt * 64 + r) * DDIM + c * 8);
        }
        __syncthreads();
        #pragma unroll
        for (int st = 0; st < 4; ++st) {
            bf16x8 a0 = *(const bf16x8*)&KtS[st * 16 + lid][quad * 8];
            bf16x8 a1 = *(const bf16x8*)&KtS[st * 16 + lid][32 + quad * 8];
            f32x4 c = __builtin_amdgcn_mfma_f32_16x16x32_bf16(a0, qf0, zero, 0, 0, 0);
            c = __builtin_amdgcn_mfma_f32_16x16x32_bf16(a1, qf1, c, 0, 0, 0);
            #pragma unroll
            for (int r = 0; r < 4; ++r) rsum += __expf(C0 * c[r]);
        }
    }
    rsum += __shfl_xor(rsum, 16, 64);
    rsum += __shfl_xor(rsum, 32, 64);
    const float rinv = 1.f / rsum;

    // ---------------- pass 2: attn write + PV ----------------
    f32x4 oacc[4] = {zero, zero, zero, zero};
    const size_t abase = ((size_t)((b * 8 + h) * LLEN + myq)) * LLEN;

    for (int kt = 0; kt < 16; ++kt) {
        __syncthreads();
        #pragma unroll
        for (int rep = 0; rep < 2; ++rep) {
            int s = tid + rep * 256;
            int r = s >> 3, c = s & 7;
            *(bf16x8*)&KtS[r][c * 8] =
                *(const bf16x8*)(Kb + kbase + (size_t)(kt * 64 + r) * DDIM + c * 8);
            *(bf16x8*)&VtS[r][c * 8] =
                *(const bf16x8*)(VtG + vbase + (size_t)r * LLEN + kt * 64 + c * 8);
        }
        __syncthreads();
        #pragma unroll
        for (int st = 0; st < 4; ++st) {
            bf16x8 a0 = *(const bf16x8*)&KtS[st * 16 + lid][quad * 8];
            bf16x8 a1 = *(const bf16x8*)&KtS[st * 16 + lid][32 + quad * 8];
            f32x4 c = __builtin_amdgcn_mfma_f32_16x16x32_bf16(a0, qf0, zero, 0, 0, 0);
            c = __builtin_amdgcn_mfma_f32_16x16x32_bf16(a1, qf1, c, 0, 0, 0);
            f32x4 p;
            bf16x4 pk;
            #pragma unroll
            for (int r = 0; r < 4; ++r) {
                p[r] = __expf(C0 * c[r]) * rinv;
                pk[r] = f2bf(p[r]);
            }
            // attn[b,h,myq, kt*64+st*16+quad*4 .. +3]
            *(f32x4*)(attn_out + abase + kt * 64 + st * 16 + quad * 4) = p;
            *(bf16x4*)&PtS[w][lid][st * 16 + quad * 4] = pk;
        }
        __syncthreads();
        #pragma unroll
        for (int kc = 0; kc < 2; ++kc) {
            bf16x8 pa = *(const bf16x8*)&PtS[w][lid][kc * 32 + quad * 8];
            #pragma unroll
            for (int nt = 0; nt < 4; ++nt) {
                bf16x8 vb = *(const bf16x8*)&VtS[nt * 16 + lid][kc * 32 + quad * 8];
                oacc[nt] = __builtin_amdgcn_mfma_f32_16x16x32_bf16(pa, vb, oacc[nt], 0, 0, 0);
            }
        }
    }

    // O epilogue: C layout row = quad*4+reg (query), col = lid (d within nt)
    #pragma unroll
    for (int nt = 0; nt < 4; ++nt)
        #pragma unroll
        for (int r = 0; r < 4; ++r)
            o_out[(size_t)(b * LLEN + q0 + w * 16 + quad * 4 + r) * DDIM + h * 64 + nt * 16 + lid] = oacc[nt][r];
}

// ---------------------------------------------------------------------------
__device__ inline void block_reduce2(float& a, float& b) {
    #pragma unroll
    for (int off = 32; off > 0; off >>= 1) {
        a += __shfl_down(a, off, 64);
        b += __shfl_down(b, off, 64);
    }
    __shared__ float wa[4], wb[4];
    int lane = threadIdx.x & 63, w = threadIdx.x >> 6;
    if (lane == 0) { wa[w] = a; wb[w] = b; }
    __syncthreads();
    if (threadIdx.x == 0) {
        wa[0] = wa[0] + wa[1] + wa[2] + wa[3];
        wb[0] = wb[0] + wb[1] + wb[2] + wb[3];
    }
    __syncthreads();
    a = wa[0];
    b = wb[0];
}

__global__ __launch_bounds__(256) void film_ln_kernel(
    const float* __restrict__ X, const float* __restrict__ en_g,
    const float* __restrict__ en_b, const float* __restrict__ film,
    float* __restrict__ HS)
{
    const int row = blockIdx.x;
    const int b = row >> 10;
    const int tid = threadIdx.x;
    const size_t base = (size_t)row * DDIM;

    float x0 = X[base + tid];
    float x1 = X[base + 256 + tid];
    float s = x0 + x1;
    float s2 = x0 * x0 + x1 * x1;
    block_reduce2(s, s2);
    float mean = s * (1.f / 512.f);
    float var = s2 * (1.f / 512.f) - mean * mean;
    float inv = rsqrtf(var + 1e-5f);

    #pragma unroll
    for (int l = 0; l < 2; ++l) {
        int d = tid + l * 256;
        float x = (l == 0) ? x0 : x1;
        float nh = (x - mean) * inv * en_g[d] + en_b[d];
        float sc = film[b * 1024 + d];
        float sh = film[b * 1024 + 512 + d];
        float hv = nh * (1.f + sc) + sh;
        HS[base + d] = hv / (1.f + __expf(-hv));
    }
}

__global__ __launch_bounds__(256) void final_ln_kernel(
    const float* __restrict__ H2, const float* __restrict__ resid,
    const float* __restrict__ g, const float* __restrict__ bta,
    float* __restrict__ out)
{
    const int row = blockIdx.x;
    const int tid = threadIdx.x;
    const size_t base = (size_t)row * DDIM;

    float x0 = H2[base + tid] + resid[base + tid];
    float x1 = H2[base + 256 + tid] + resid[base + 256 + tid];
    float s = x0 + x1;
    float s2 = x0 * x0 + x1 * x1;
    block_reduce2(s, s2);
    float mean = s * (1.f / 512.f);
    float var = s2 * (1.f / 512.f) - mean * mean;
    float inv = rsqrtf(var + 1e-6f);

    #pragma unroll
    for (int l = 0; l < 2; ++l) {
        int d = tid + l * 256;
        float x = (l == 0) ? x0 : x1;
        out[base + d] = (x - mean) * inv * g[d] + bta[d];
    }
}

// ---------------------------------------------------------------------------
extern "C" void kernel_launch(void* const* d_in, const int* in_sizes, int n_in,
                              void* d_out, int out_size, void* d_ws, size_t ws_size,
                              hipStream_t stream)
{
    const float* q      = (const float*)d_in[0];
    const float* k      = (const float*)d_in[1];
    const float* v      = (const float*)d_in[2];
    const float* latent = (const float*)d_in[3];
    const float* Wq  = (const float*)d_in[4];
    const float* bq  = (const float*)d_in[5];
    const float* Wk  = (const float*)d_in[6];
    const float* bk  = (const float*)d_in[7];
    const float* Wv  = (const float*)d_in[8];
    const float* bv  = (const float*)d_in[9];
    const float* Wfc = (const float*)d_in[10];
    const float* bfc = (const float*)d_in[11];
    const float* Ws1 = (const float*)d_in[12];
    const float* bs1 = (const float*)d_in[13];
    const float* Ws2 = (const float*)d_in[14];
    const float* bs2 = (const float*)d_in[15];
    const float* en_g = (const float*)d_in[16];
    const float* en_b = (const float*)d_in[17];
    const float* ln_g = (const float*)d_in[18];
    const float* ln_b = (const float*)d_in[19];

    float* out  = (float*)d_out;            // [8192, 512]
    float* attn = out + ROWELEM;            // [8, 8, 1024, 1024]

    char* ws = (char*)d_ws;
    float*  Ob   = (float*)(ws + 0);               // 16.8 MB fp32
    __bf16* Qb   = (__bf16*)(ws + 16777216);       // 8.4 MB bf16
    __bf16* Kb   = (__bf16*)(ws + 25165824);
    __bf16* Vb   = (__bf16*)(ws + 33554432);
    __bf16* VtG  = (__bf16*)(ws + 41943040);
    float*  film = (float*)(ws + 50331648);        // 32 KB
    float*  F1   = (float*)(ws + 16777216);        // alias Qb/Kb (dead after attn)
    float*  HS   = (float*)(ws + 33554432);        // alias Vb/VtG (dead after attn)
    float*  H2   = (float*)(ws + 0);               // alias Ob (dead after FC)

    dim3 ggrid(8, 128);

    gemm_bias_bf16_kernel<<<ggrid, 256, 0, stream>>>(q, Wq, bq, Qb, NROW, 512, 512);
    gemm_bias_bf16_kernel<<<ggrid, 256, 0, stream>>>(k, Wk, bk, Kb, NROW, 512, 512);
    gemm_bias_bf16_kernel<<<ggrid, 256, 0, stream>>>(v, Wv, bv, Vb, NROW, 512, 512);
    vtrans_kernel<<<1024, 256, 0, stream>>>(Vb, VtG);

    film_latent_kernel<<<dim3(BB, 4), 256, 0, stream>>>(latent, Ws1, bs1, film);

    attn_mfma_kernel<<<1024, 256, 0, stream>>>(Qb, Kb, VtG, attn, Ob);

    gemm_bias_kernel<<<ggrid, 256, 0, stream>>>(Ob, Wfc, bfc, F1, NROW, 512, 512);
    film_ln_kernel<<<NROW, 256, 0, stream>>>(F1, en_g, en_b, film, HS);
    gemm_bias_kernel<<<ggrid, 256, 0, stream>>>(HS, Ws2, bs2, H2, NROW, 512, 512);
    final_ln_kernel<<<NROW, 256, 0, stream>>>(H2, q, ln_g, ln_b, out);
}